// Round 7
// baseline (132.175 us; speedup 1.0000x reference)
//
#include <hip/hip_runtime.h>

#define NSEG 21
#define NLBL 20
#define DIM  32
#define SP   8       // pixel slices per (b,d) in k_moments
#define NBX  64      // k_var blocks per batch (N/1024)
#define NREP 16
#define DV   0.5f
#define DD   3.0f
#define BATCH 8

// ws layout (floats), all deterministically overwritten every call:
//   part : [BATCH][DIM][SP][NLBL]   sums partials      40960
//   cpart: [BATCH][SP][NLBL]        count partials      1280
//   vpart: [BATCH][NBX][NLBL]       var partials       10240
#define P_OFF  0
#define C_OFF  (BATCH * DIM * SP * NLBL)
#define V_OFF  (C_OFF + BATCH * SP * NLBL)

// One-hot register accumulation (labels 1..20; label 0 never used by the loss).
// No LDS atomics, no global atomics, no zero-init required.
__global__ __launch_bounds__(256)
void k_moments(const float* __restrict__ emb, const int* __restrict__ seg,
               float* __restrict__ ws, int N) {
  __shared__ float red[8 * NLBL];
  const int tid = threadIdx.x;
  const int sp = blockIdx.x, d = blockIdx.y, b = blockIdx.z;
  const int n0 = sp * 8192;
  const float4* e4 = (const float4*)(emb + ((size_t)b * DIM + d) * N + n0) + tid;
  const int4*   g4 = (const int4*)(seg + (size_t)b * N + n0) + tid;

  float acc[NLBL], cnt[NLBL];
  #pragma unroll
  for (int l = 0; l < NLBL; ++l) { acc[l] = 0.f; cnt[l] = 0.f; }

  if (d == 0) {
    #pragma unroll
    for (int u = 0; u < 8; u += 4) {
      float4 e[4]; int4 s[4];
      #pragma unroll
      for (int k = 0; k < 4; ++k) { e[k] = e4[(u + k) * 256]; s[k] = g4[(u + k) * 256]; }
      #pragma unroll
      for (int k = 0; k < 4; ++k) {
        #pragma unroll
        for (int l = 0; l < NLBL; ++l) {
          const int lab = l + 1;
          if (s[k].x == lab) { acc[l] += e[k].x; cnt[l] += 1.f; }
          if (s[k].y == lab) { acc[l] += e[k].y; cnt[l] += 1.f; }
          if (s[k].z == lab) { acc[l] += e[k].z; cnt[l] += 1.f; }
          if (s[k].w == lab) { acc[l] += e[k].w; cnt[l] += 1.f; }
        }
      }
    }
  } else {
    #pragma unroll
    for (int u = 0; u < 8; u += 4) {
      float4 e[4]; int4 s[4];
      #pragma unroll
      for (int k = 0; k < 4; ++k) { e[k] = e4[(u + k) * 256]; s[k] = g4[(u + k) * 256]; }
      #pragma unroll
      for (int k = 0; k < 4; ++k) {
        #pragma unroll
        for (int l = 0; l < NLBL; ++l) {
          const int lab = l + 1;
          if (s[k].x == lab) acc[l] += e[k].x;
          if (s[k].y == lab) acc[l] += e[k].y;
          if (s[k].z == lab) acc[l] += e[k].z;
          if (s[k].w == lab) acc[l] += e[k].w;
        }
      }
    }
  }

  const int wave = tid >> 6, lane = tid & 63;
  #pragma unroll
  for (int l = 0; l < NLBL; ++l) {
    float a = acc[l];
    #pragma unroll
    for (int off = 32; off; off >>= 1) a += __shfl_xor(a, off, 64);
    if (lane == 0) red[wave * NLBL + l] = a;
  }
  __syncthreads();
  if (tid < NLBL) {
    const float v = red[tid] + red[NLBL + tid] + red[2 * NLBL + tid] + red[3 * NLBL + tid];
    ws[P_OFF + (((size_t)(b * DIM + d) * SP + sp) * NLBL) + tid] = v;
  }
  if (d == 0) {
    __syncthreads();
    #pragma unroll
    for (int l = 0; l < NLBL; ++l) {
      float c = cnt[l];
      #pragma unroll
      for (int off = 32; off; off >>= 1) c += __shfl_xor(c, off, 64);
      if (lane == 0) red[wave * NLBL + l] = c;
    }
    __syncthreads();
    if (tid < NLBL) {
      const float c = red[tid] + red[NLBL + tid] + red[2 * NLBL + tid] + red[3 * NLBL + tid];
      ws[C_OFF + ((size_t)b * SP + sp) * NLBL + tid] = c;
    }
  }
}

// float4 pixels; means from partials; hinge; per-block deterministic vpart store.
__global__ __launch_bounds__(256)
void k_var(const float* __restrict__ emb, const int* __restrict__ seg,
           float* __restrict__ ws, int N) {
  __shared__ float s_m[NSEG * 33];     // row 0 (label 0) stays zero
  __shared__ float s_c[NLBL];
  __shared__ float s_v[NREP * NSEG];
  const int tid = threadIdx.x;
  const int bx = blockIdx.x, b = blockIdx.y;
  if (tid < NLBL) {
    float c = 0.f;
    #pragma unroll
    for (int sp = 0; sp < SP; ++sp) c += ws[C_OFF + ((size_t)b * SP + sp) * NLBL + tid];
    s_c[tid] = fmaxf(c, 1.f);
  }
  for (int i = tid; i < NSEG * 33; i += 256) s_m[i] = 0.f;
  for (int i = tid; i < NREP * NSEG; i += 256) s_v[i] = 0.f;
  __syncthreads();
  for (int i = tid; i < NLBL * DIM; i += 256) {
    const int l = i >> 5, d = i & 31;
    float sum = 0.f;
    #pragma unroll
    for (int sp = 0; sp < SP; ++sp)
      sum += ws[P_OFF + (((size_t)(b * DIM + d) * SP + sp) * NLBL) + l];
    s_m[(l + 1) * 33 + d] = sum / s_c[l];
  }
  __syncthreads();

  const int n0 = bx * 1024;
  const int4 sl = *((const int4*)(seg + (size_t)b * N + n0) + tid);
  const float4* e4 = (const float4*)(emb + (size_t)b * DIM * N + n0) + tid;
  const int mx = sl.x * 33, my = sl.y * 33, mz = sl.z * 33, mw = sl.w * 33;
  float q0 = 0.f, q1 = 0.f, q2 = 0.f, q3 = 0.f;
  #pragma unroll 8
  for (int d = 0; d < DIM; ++d) {
    const float4 e = e4[d * (65536 / 4)];
    float t;
    t = e.x - s_m[mx + d]; q0 += t * t;
    t = e.y - s_m[my + d]; q1 += t * t;
    t = e.z - s_m[mz + d]; q2 += t * t;
    t = e.w - s_m[mw + d]; q3 += t * t;
  }
  const int rb = (tid & (NREP - 1)) * NSEG;
  if (sl.x > 0) { const float r = sqrtf(q0) - DV; if (r > 0.f) atomicAdd(&s_v[rb + sl.x], r * r); }
  if (sl.y > 0) { const float r = sqrtf(q1) - DV; if (r > 0.f) atomicAdd(&s_v[rb + sl.y], r * r); }
  if (sl.z > 0) { const float r = sqrtf(q2) - DV; if (r > 0.f) atomicAdd(&s_v[rb + sl.z], r * r); }
  if (sl.w > 0) { const float r = sqrtf(q3) - DV; if (r > 0.f) atomicAdd(&s_v[rb + sl.w], r * r); }
  __syncthreads();
  if (tid < NLBL) {
    float v = 0.f;
    #pragma unroll
    for (int r = 0; r < NREP; ++r) v += s_v[r * NSEG + (tid + 1)];
    ws[V_OFF + ((size_t)b * NBX + bx) * NLBL + tid] = v;
  }
}

__global__ __launch_bounds__(256)
void k_final(const float* __restrict__ ws, float* __restrict__ out) {
  __shared__ float s_m[NLBL * 33];
  __shared__ float s_c[NLBL];
  __shared__ float s_vs[NLBL];
  __shared__ int   s_p[NLBL];
  __shared__ float s_dl;
  const int tid = threadIdx.x;
  float acc_v = 0.f, acc_d = 0.f;
  for (int b = 0; b < BATCH; ++b) {
    __syncthreads();
    if (tid < NLBL) {
      float c = 0.f;
      #pragma unroll
      for (int sp = 0; sp < SP; ++sp) c += ws[C_OFF + ((size_t)b * SP + sp) * NLBL + tid];
      s_c[tid] = c;
      s_p[tid] = (c > 0.f) ? 1 : 0;
      float v = 0.f;
      for (int bx = 0; bx < NBX; ++bx) v += ws[V_OFF + ((size_t)b * NBX + bx) * NLBL + tid];
      s_vs[tid] = v;
    }
    if (tid == 0) s_dl = 0.f;
    __syncthreads();
    for (int i = tid; i < NLBL * DIM; i += 256) {
      const int l = i >> 5, d = i & 31;
      float sum = 0.f;
      #pragma unroll
      for (int sp = 0; sp < SP; ++sp)
        sum += ws[P_OFF + (((size_t)(b * DIM + d) * SP + sp) * NLBL) + l];
      s_m[l * 33 + d] = sum / fmaxf(s_c[l], 1.f);
    }
    __syncthreads();
    float dl = 0.f;
    for (int p = tid; p < NLBL * NLBL; p += 256) {
      const int i = p / NLBL, j = p - (p / NLBL) * NLBL;
      if (i != j && s_p[i] && s_p[j]) {
        float sq = 0.f;
        #pragma unroll
        for (int d = 0; d < DIM; ++d) {
          const float t = s_m[i * 33 + d] - s_m[j * 33 + d];
          sq += t * t;
        }
        const float r = DD - sqrtf(sq);
        if (r > 0.f) dl += r * r;
      }
    }
    atomicAdd(&s_dl, dl);
    __syncthreads();
    if (tid == 0) {
      float nl = 0.f, var = 0.f;
      for (int l = 0; l < NLBL; ++l)
        if (s_p[l]) { nl += 1.f; var += s_vs[l] / s_c[l]; }
      acc_v += (nl > 0.f) ? var / nl : 0.f;
      acc_d += (nl > 1.f) ? s_dl / fmaxf(nl * (nl - 1.f), 1.f) * 0.5f : 0.f;
    }
  }
  if (tid == 0) {
    out[0] = acc_v / (float)BATCH;
    out[1] = acc_d / (float)BATCH;
    out[2] = 0.f;
  }
}

extern "C" void kernel_launch(void* const* d_in, const int* in_sizes, int n_in,
                              void* d_out, int out_size, void* d_ws, size_t ws_size,
                              hipStream_t stream) {
  const float* emb = (const float*)d_in[0];
  const int*   seg = (const int*)d_in[1];
  float* out = (float*)d_out;
  float* ws  = (float*)d_ws;
  const int N = in_sizes[1] / BATCH;              // 65536

  k_moments<<<dim3(SP, DIM, BATCH), 256, 0, stream>>>(emb, seg, ws, N);
  k_var    <<<dim3(NBX, BATCH), 256, 0, stream>>>(emb, seg, ws, N);
  k_final  <<<1, 256, 0, stream>>>(ws, out);
}

// Round 8
// 91.780 us; speedup vs baseline: 1.4401x; 1.4401x over previous
//
#include <hip/hip_runtime.h>

#define NSEG 21
#define NLBL 20
#define DIM  32
#define SP   16      // pixel slices per (b,d-chunk) in k_moments
#define DPB  4       // dims per k_moments block
#define NBXV 128     // k_var blocks per batch (N/512)
#define NREP 16
#define DV   0.5f
#define DD   3.0f
#define BATCH 8

// ws float layout (all deterministically overwritten every call):
#define P_OFF  0                       // part  [B][DIM][NLBL][SP]  81920
#define C_OFF  81920                   // cpart [B][SP][NLBL]        2560
#define M_OFF  84480                   // means [B][NLBL*DIM]        5120
#define CN_OFF 89600                   // cnt   [B][NLBL]             160
#define V_OFF  89760                   // vpart [B][NLBL][NBXV]     20480
#define PB_OFF 110240                  // pb    [B][2]                 16

// One-hot register accumulation, 4 dims per block (seg read amortized 4x).
__global__ __launch_bounds__(256)
void k_moments(const float* __restrict__ emb, const int* __restrict__ seg,
               float* __restrict__ ws, int N) {
  __shared__ float red[4 * NLBL];
  const int tid = threadIdx.x;
  const int sp = blockIdx.x, dz = blockIdx.y, b = blockIdx.z;
  const int n0 = sp * 4096;
  const int wave = tid >> 6, lane = tid & 63;

  const int4* g4 = (const int4*)(seg + (size_t)b * N + n0) + tid;
  int4 s[4];
  #pragma unroll
  for (int u = 0; u < 4; ++u) s[u] = g4[u * 256];

  if (dz == 0) {                       // counts once per (b,sp)
    float cnt[NLBL];
    #pragma unroll
    for (int l = 0; l < NLBL; ++l) cnt[l] = 0.f;
    #pragma unroll
    for (int u = 0; u < 4; ++u) {
      #pragma unroll
      for (int l = 0; l < NLBL; ++l) {
        const int lab = l + 1;
        if (s[u].x == lab) cnt[l] += 1.f;
        if (s[u].y == lab) cnt[l] += 1.f;
        if (s[u].z == lab) cnt[l] += 1.f;
        if (s[u].w == lab) cnt[l] += 1.f;
      }
    }
    #pragma unroll
    for (int l = 0; l < NLBL; ++l) {
      float c = cnt[l];
      #pragma unroll
      for (int off = 32; off; off >>= 1) c += __shfl_xor(c, off, 64);
      if (lane == 0) red[wave * NLBL + l] = c;
    }
    __syncthreads();
    if (tid < NLBL)
      ws[C_OFF + ((size_t)b * SP + sp) * NLBL + tid] =
          red[tid] + red[NLBL + tid] + red[2 * NLBL + tid] + red[3 * NLBL + tid];
  }

  for (int dd = 0; dd < DPB; ++dd) {
    const int d = dz * DPB + dd;
    const float4* e4 = (const float4*)(emb + ((size_t)b * DIM + d) * N + n0) + tid;
    float4 e[4];
    #pragma unroll
    for (int u = 0; u < 4; ++u) e[u] = e4[u * 256];
    float acc[NLBL];
    #pragma unroll
    for (int l = 0; l < NLBL; ++l) acc[l] = 0.f;
    #pragma unroll
    for (int u = 0; u < 4; ++u) {
      #pragma unroll
      for (int l = 0; l < NLBL; ++l) {
        const int lab = l + 1;
        if (s[u].x == lab) acc[l] += e[u].x;
        if (s[u].y == lab) acc[l] += e[u].y;
        if (s[u].z == lab) acc[l] += e[u].z;
        if (s[u].w == lab) acc[l] += e[u].w;
      }
    }
    __syncthreads();                   // red reuse across dd / counts
    #pragma unroll
    for (int l = 0; l < NLBL; ++l) {
      float a = acc[l];
      #pragma unroll
      for (int off = 32; off; off >>= 1) a += __shfl_xor(a, off, 64);
      if (lane == 0) red[wave * NLBL + l] = a;
    }
    __syncthreads();
    if (tid < NLBL)
      ws[P_OFF + (((size_t)(b * DIM + d) * NLBL) + tid) * SP + sp] =
          red[tid] + red[NLBL + tid] + red[2 * NLBL + tid] + red[3 * NLBL + tid];
  }
}

// Canonical means + counts (8 blocks). part slices are contiguous (16 floats).
__global__ __launch_bounds__(256)
void k_means(float* __restrict__ ws) {
  __shared__ float s_ct[SP * NLBL];
  __shared__ float s_c[NLBL];
  const int b = blockIdx.x, tid = threadIdx.x;
  for (int i = tid; i < SP * NLBL; i += 256) s_ct[i] = ws[C_OFF + (size_t)b * SP * NLBL + i];
  __syncthreads();
  if (tid < NLBL) {
    float c = 0.f;
    #pragma unroll
    for (int sp = 0; sp < SP; ++sp) c += s_ct[sp * NLBL + tid];
    ws[CN_OFF + b * NLBL + tid] = c;
    s_c[tid] = fmaxf(c, 1.f);
  }
  __syncthreads();
  for (int i = tid; i < NLBL * DIM; i += 256) {
    const int l = i >> 5;              // i = l*32 + d
    const float4* p4 = (const float4*)(ws + P_OFF + ((size_t)b * DIM * NLBL + i) * 0);
    // real base: part[((b*32+d)*20+l)*16]
    const int d = i & 31;
    const float4* q4 = (const float4*)(ws + P_OFF + (((size_t)(b * DIM + d) * NLBL) + l) * SP);
    float sum = 0.f;
    #pragma unroll
    for (int k = 0; k < SP / 4; ++k) {
      const float4 v = q4[k];
      sum += v.x + v.y + v.z + v.w;
    }
    (void)p4;
    ws[M_OFF + (size_t)b * NLBL * DIM + i] = sum / s_c[l];
  }
}

// 2 px/thread, 1024 blocks; means preloaded from canonical buffer.
__global__ __launch_bounds__(256)
void k_var(const float* __restrict__ emb, const int* __restrict__ seg,
           float* __restrict__ ws, int N) {
  __shared__ float s_m[NSEG * 33];     // row 0 stays zero
  __shared__ float s_v[NREP * NSEG];
  const int tid = threadIdx.x;
  const int bx = blockIdx.x, b = blockIdx.y;
  for (int i = tid; i < NSEG * 33; i += 256) s_m[i] = 0.f;
  for (int i = tid; i < NREP * NSEG; i += 256) s_v[i] = 0.f;
  __syncthreads();
  if (tid < 160) {
    const float4 v = ((const float4*)(ws + M_OFF + (size_t)b * NLBL * DIM))[tid];
    const int flat = tid * 4, l = flat >> 5, d = flat & 31;
    float* dst = &s_m[(l + 1) * 33 + d];
    dst[0] = v.x; dst[1] = v.y; dst[2] = v.z; dst[3] = v.w;
  }
  __syncthreads();

  const int n0 = bx * 512;
  const int2 sl = ((const int2*)(seg + (size_t)b * N + n0))[tid];
  const float2* e2 = (const float2*)(emb + (size_t)b * DIM * N + n0) + tid;
  const int mx = sl.x * 33, my = sl.y * 33;
  float q0 = 0.f, q1 = 0.f;
  #pragma unroll 8
  for (int d = 0; d < DIM; ++d) {
    const float2 e = e2[d * (65536 / 2)];
    float t;
    t = e.x - s_m[mx + d]; q0 += t * t;
    t = e.y - s_m[my + d]; q1 += t * t;
  }
  const int rb = (tid & (NREP - 1)) * NSEG;
  if (sl.x > 0) { const float r = sqrtf(q0) - DV; if (r > 0.f) atomicAdd(&s_v[rb + sl.x], r * r); }
  if (sl.y > 0) { const float r = sqrtf(q1) - DV; if (r > 0.f) atomicAdd(&s_v[rb + sl.y], r * r); }
  __syncthreads();
  if (tid < NLBL) {
    float v = 0.f;
    #pragma unroll
    for (int r = 0; r < NREP; ++r) v += s_v[r * NSEG + (tid + 1)];
    ws[V_OFF + ((size_t)b * NLBL + tid) * NBXV + bx] = v;
  }
}

// One block per batch; fully parallel reductions; writes per-batch (vb, db).
__global__ __launch_bounds__(256)
void k_final(float* __restrict__ ws) {
  __shared__ float s_m[NLBL * 33];
  __shared__ float s_c[NLBL];
  __shared__ float s_vs[NLBL];
  __shared__ int   s_p[NLBL];
  __shared__ float s_red[4];
  const int b = blockIdx.x, tid = threadIdx.x;
  const int wave = tid >> 6, lane = tid & 63;

  if (tid < 160) {                     // vpart reduce: 8 threads per label
    const int g = tid >> 3, j = tid & 7;
    const float4* v4 = (const float4*)(ws + V_OFF + ((size_t)b * NLBL + g) * NBXV + j * 16);
    float s = 0.f;
    #pragma unroll
    for (int k = 0; k < 4; ++k) { const float4 v = v4[k]; s += v.x + v.y + v.z + v.w; }
    s += __shfl_xor(s, 1, 64); s += __shfl_xor(s, 2, 64); s += __shfl_xor(s, 4, 64);
    if (j == 0) s_vs[g] = s;
  }
  if (tid < NLBL) {
    const float c = ws[CN_OFF + b * NLBL + tid];
    s_c[tid] = c;
    s_p[tid] = (c > 0.f) ? 1 : 0;
  }
  if (tid < 160) {
    const float4 v = ((const float4*)(ws + M_OFF + (size_t)b * NLBL * DIM))[tid];
    const int flat = tid * 4, l = flat >> 5, d = flat & 31;
    float* dst = &s_m[l * 33 + d];
    dst[0] = v.x; dst[1] = v.y; dst[2] = v.z; dst[3] = v.w;
  }
  __syncthreads();

  float dl = 0.f;
  for (int p = tid; p < NLBL * NLBL; p += 256) {
    const int i = p / NLBL, j = p - (p / NLBL) * NLBL;
    if (i != j && s_p[i] && s_p[j]) {
      float sq = 0.f;
      #pragma unroll
      for (int d = 0; d < DIM; ++d) {
        const float t = s_m[i * 33 + d] - s_m[j * 33 + d];
        sq += t * t;
      }
      const float r = DD - sqrtf(sq);
      if (r > 0.f) dl += r * r;
    }
  }
  #pragma unroll
  for (int off = 32; off; off >>= 1) dl += __shfl_xor(dl, off, 64);
  if (lane == 0) s_red[wave] = dl;
  __syncthreads();
  if (tid == 0) {
    const float dsum = s_red[0] + s_red[1] + s_red[2] + s_red[3];
    float nl = 0.f, var = 0.f;
    for (int l = 0; l < NLBL; ++l)
      if (s_p[l]) { nl += 1.f; var += s_vs[l] / s_c[l]; }
    ws[PB_OFF + b * 2]     = (nl > 0.f) ? var / nl : 0.f;
    ws[PB_OFF + b * 2 + 1] = (nl > 1.f) ? dsum / fmaxf(nl * (nl - 1.f), 1.f) * 0.5f : 0.f;
  }
}

__global__ __launch_bounds__(64)
void k_out(const float* __restrict__ ws, float* __restrict__ out) {
  const int tid = threadIdx.x;
  float v = 0.f, d = 0.f;
  if (tid < BATCH) {
    v = ws[PB_OFF + tid * 2];
    d = ws[PB_OFF + tid * 2 + 1];
  }
  #pragma unroll
  for (int off = 4; off; off >>= 1) { v += __shfl_xor(v, off, 64); d += __shfl_xor(d, off, 64); }
  if (tid == 0) {
    out[0] = v / (float)BATCH;
    out[1] = d / (float)BATCH;
    out[2] = 0.f;
  }
}

extern "C" void kernel_launch(void* const* d_in, const int* in_sizes, int n_in,
                              void* d_out, int out_size, void* d_ws, size_t ws_size,
                              hipStream_t stream) {
  const float* emb = (const float*)d_in[0];
  const int*   seg = (const int*)d_in[1];
  float* out = (float*)d_out;
  float* ws  = (float*)d_ws;
  const int N = in_sizes[1] / BATCH;   // 65536

  k_moments<<<dim3(SP, DIM / DPB, BATCH), 256, 0, stream>>>(emb, seg, ws, N);
  k_means  <<<dim3(BATCH), 256, 0, stream>>>(ws);
  k_var    <<<dim3(NBXV, BATCH), 256, 0, stream>>>(emb, seg, ws, N);
  k_final  <<<dim3(BATCH), 256, 0, stream>>>(ws);
  k_out    <<<1, 64, 0, stream>>>(ws, out);
}

// Round 9
// 57.744 us; speedup vs baseline: 2.2890x; 1.5894x over previous
//
#include <hip/hip_runtime.h>

#define NSEG 21
#define NLBL 20
#define DIM  32
#define NS   128     // k_moments blocks (slots) per batch
#define PXB  512     // pixels per k_moments block
#define NBXV 128     // k_var blocks per batch (2 px/thread)
#define NREP 16
#define DV   0.5f
#define DD   3.0f
#define BATCH 8
#define N_PIX 65536

using short8 = __attribute__((ext_vector_type(8))) short;
using f32x4  = __attribute__((ext_vector_type(4))) float;

// ws float layout (all deterministically overwritten every call):
#define P_OFF  0         // part  [B][32][20][NS]   655360
#define C2_OFF 655360    // cpart [B][20][NS]        20480
#define M_OFF  675840    // means [B][l*32+d]         5120
#define CN_OFF 680960    // cnt   [B][20]              160
#define V_OFF  681120    // vpart [B][20][NBXV]      20480
#define PB_OFF 701600    // pb    [B][2]                16

__device__ inline short bf16rne(float f) {
  const unsigned u = __builtin_bit_cast(unsigned, f);
  return (short)((u + 0x7FFFu + ((u >> 16) & 1u)) >> 16);
}

// Segment sums+counts via MFMA: sums[d][l] = emb[d][:] . onehot[:][l].
// A = emb (M=dims, 2 tiles of 16), B = onehot from seg (N=labels, 2 tiles),
// K = 32 pixels/step. Counts via A=ones. No atomics anywhere.
__global__ __launch_bounds__(256)
void k_moments(const float* __restrict__ emb, const int* __restrict__ seg,
               float* __restrict__ ws) {
  __shared__ float lred[4 * 1536];
  const int tid = threadIdx.x;
  const int wv = tid >> 6, lane = tid & 63;
  const int slot = blockIdx.x;               // 0..NS-1
  const int b = blockIdx.y;
  const int lr = lane & 15, lg = lane >> 4;  // frag row/col, k-group

  const float* rowA0 = emb + ((size_t)b * DIM + lr) * N_PIX;
  const float* rowA1 = rowA0 + (size_t)16 * N_PIX;
  const int*   segb  = seg + (size_t)b * N_PIX;

  f32x4 s00 = {0,0,0,0}, s01 = {0,0,0,0}, s10 = {0,0,0,0}, s11 = {0,0,0,0};
  f32x4 c0  = {0,0,0,0}, c1  = {0,0,0,0};

  short8 ones;
  #pragma unroll
  for (int j = 0; j < 8; ++j) ones[j] = (short)0x3F80;

  const int nbase = slot * PXB + wv * 32;
  #pragma unroll 2
  for (int t = 0; t < 4; ++t) {
    const int koff = nbase + t * 128 + lg * 8;
    const float4 a00 = *(const float4*)(rowA0 + koff);
    const float4 a01 = *(const float4*)(rowA0 + koff + 4);
    const float4 a10 = *(const float4*)(rowA1 + koff);
    const float4 a11 = *(const float4*)(rowA1 + koff + 4);
    const int4   g0  = *(const int4*)(segb + koff);
    const int4   g1  = *(const int4*)(segb + koff + 4);

    short8 fa0, fa1, fb0, fb1;
    fa0[0] = bf16rne(a00.x); fa0[1] = bf16rne(a00.y);
    fa0[2] = bf16rne(a00.z); fa0[3] = bf16rne(a00.w);
    fa0[4] = bf16rne(a01.x); fa0[5] = bf16rne(a01.y);
    fa0[6] = bf16rne(a01.z); fa0[7] = bf16rne(a01.w);
    fa1[0] = bf16rne(a10.x); fa1[1] = bf16rne(a10.y);
    fa1[2] = bf16rne(a10.z); fa1[3] = bf16rne(a10.w);
    fa1[4] = bf16rne(a11.x); fa1[5] = bf16rne(a11.y);
    fa1[6] = bf16rne(a11.z); fa1[7] = bf16rne(a11.w);
    const int sv0 = g0.x, sv1 = g0.y, sv2 = g0.z, sv3 = g0.w;
    const int sv4 = g1.x, sv5 = g1.y, sv6 = g1.z, sv7 = g1.w;
    const int lab0 = lr + 1, lab1 = lr + 17;
    fb0[0] = (sv0 == lab0) ? (short)0x3F80 : (short)0;
    fb0[1] = (sv1 == lab0) ? (short)0x3F80 : (short)0;
    fb0[2] = (sv2 == lab0) ? (short)0x3F80 : (short)0;
    fb0[3] = (sv3 == lab0) ? (short)0x3F80 : (short)0;
    fb0[4] = (sv4 == lab0) ? (short)0x3F80 : (short)0;
    fb0[5] = (sv5 == lab0) ? (short)0x3F80 : (short)0;
    fb0[6] = (sv6 == lab0) ? (short)0x3F80 : (short)0;
    fb0[7] = (sv7 == lab0) ? (short)0x3F80 : (short)0;
    fb1[0] = (sv0 == lab1) ? (short)0x3F80 : (short)0;
    fb1[1] = (sv1 == lab1) ? (short)0x3F80 : (short)0;
    fb1[2] = (sv2 == lab1) ? (short)0x3F80 : (short)0;
    fb1[3] = (sv3 == lab1) ? (short)0x3F80 : (short)0;
    fb1[4] = (sv4 == lab1) ? (short)0x3F80 : (short)0;
    fb1[5] = (sv5 == lab1) ? (short)0x3F80 : (short)0;
    fb1[6] = (sv6 == lab1) ? (short)0x3F80 : (short)0;
    fb1[7] = (sv7 == lab1) ? (short)0x3F80 : (short)0;

    s00 = __builtin_amdgcn_mfma_f32_16x16x32_bf16(fa0, fb0, s00, 0, 0, 0);
    s01 = __builtin_amdgcn_mfma_f32_16x16x32_bf16(fa0, fb1, s01, 0, 0, 0);
    s10 = __builtin_amdgcn_mfma_f32_16x16x32_bf16(fa1, fb0, s10, 0, 0, 0);
    s11 = __builtin_amdgcn_mfma_f32_16x16x32_bf16(fa1, fb1, s11, 0, 0, 0);
    c0  = __builtin_amdgcn_mfma_f32_16x16x32_bf16(ones, fb0, c0, 0, 0, 0);
    c1  = __builtin_amdgcn_mfma_f32_16x16x32_bf16(ones, fb1, c1, 0, 0, 0);
  }

  // dump 6 frags to LDS, reduce 4 waves, scatter to partials
  float* my = lred + wv * 1536 + lane * 4;
  #pragma unroll
  for (int r = 0; r < 4; ++r) {
    my[0 * 256 + r] = s00[r]; my[1 * 256 + r] = s01[r];
    my[2 * 256 + r] = s10[r]; my[3 * 256 + r] = s11[r];
    my[4 * 256 + r] = c0[r];  my[5 * 256 + r] = c1[r];
  }
  __syncthreads();
  for (int i = tid; i < 1536; i += 256)
    lred[i] = lred[i] + lred[1536 + i] + lred[2 * 1536 + i] + lred[3 * 1536 + i];
  __syncthreads();
  for (int i = tid; i < 1536; i += 256) {
    const float v = lred[i];
    const int f = i >> 8, ln = (i >> 2) & 63, r = i & 3;
    const int col = ln & 15, row = ((ln >> 4) << 2) | r;
    if (f < 4) {
      const int d = (f >> 1) * 16 + row;
      const int lcol = (f & 1) * 16 + col;
      if (lcol < NLBL)
        ws[P_OFF + (((size_t)(b * DIM + d) * NLBL) + lcol) * NS + slot] = v;
    } else {
      const int lcol = (f & 1) * 16 + col;
      if (row == 0 && lcol < NLBL)
        ws[C2_OFF + ((size_t)b * NLBL + lcol) * NS + slot] = v;
    }
  }
}

__global__ __launch_bounds__(256)
void k_means(float* __restrict__ ws) {
  __shared__ float s_c[NLBL];
  const int b = blockIdx.x, tid = threadIdx.x;
  if (tid < NLBL) {
    const float4* cp = (const float4*)(ws + C2_OFF + ((size_t)b * NLBL + tid) * NS);
    float c = 0.f;
    #pragma unroll
    for (int k = 0; k < NS / 4; ++k) { const float4 v = cp[k]; c += v.x + v.y + v.z + v.w; }
    ws[CN_OFF + b * NLBL + tid] = c;
    s_c[tid] = fmaxf(c, 1.f);
  }
  __syncthreads();
  for (int i = tid; i < NLBL * DIM; i += 256) {
    const int l = i >> 5, d = i & 31;
    const float4* pp = (const float4*)(ws + P_OFF + (((size_t)(b * DIM + d) * NLBL) + l) * NS);
    float s = 0.f;
    #pragma unroll
    for (int k = 0; k < NS / 4; ++k) { const float4 v = pp[k]; s += v.x + v.y + v.z + v.w; }
    ws[M_OFF + (size_t)b * NLBL * DIM + i] = s / s_c[l];
  }
}

// unchanged from R8 (2 px/thread, float2, means from canonical buffer)
__global__ __launch_bounds__(256)
void k_var(const float* __restrict__ emb, const int* __restrict__ seg,
           float* __restrict__ ws, int N) {
  __shared__ float s_m[NSEG * 33];
  __shared__ float s_v[NREP * NSEG];
  const int tid = threadIdx.x;
  const int bx = blockIdx.x, b = blockIdx.y;
  for (int i = tid; i < NSEG * 33; i += 256) s_m[i] = 0.f;
  for (int i = tid; i < NREP * NSEG; i += 256) s_v[i] = 0.f;
  __syncthreads();
  if (tid < 160) {
    const float4 v = ((const float4*)(ws + M_OFF + (size_t)b * NLBL * DIM))[tid];
    const int flat = tid * 4, l = flat >> 5, d = flat & 31;
    float* dst = &s_m[(l + 1) * 33 + d];
    dst[0] = v.x; dst[1] = v.y; dst[2] = v.z; dst[3] = v.w;
  }
  __syncthreads();

  const int n0 = bx * 512;
  const int2 sl = ((const int2*)(seg + (size_t)b * N + n0))[tid];
  const float2* e2 = (const float2*)(emb + (size_t)b * DIM * N + n0) + tid;
  const int mx = sl.x * 33, my = sl.y * 33;
  float q0 = 0.f, q1 = 0.f;
  #pragma unroll 8
  for (int d = 0; d < DIM; ++d) {
    const float2 e = e2[d * (N_PIX / 2)];
    float t;
    t = e.x - s_m[mx + d]; q0 += t * t;
    t = e.y - s_m[my + d]; q1 += t * t;
  }
  const int rb = (tid & (NREP - 1)) * NSEG;
  if (sl.x > 0) { const float r = sqrtf(q0) - DV; if (r > 0.f) atomicAdd(&s_v[rb + sl.x], r * r); }
  if (sl.y > 0) { const float r = sqrtf(q1) - DV; if (r > 0.f) atomicAdd(&s_v[rb + sl.y], r * r); }
  __syncthreads();
  if (tid < NLBL) {
    float v = 0.f;
    #pragma unroll
    for (int r = 0; r < NREP; ++r) v += s_v[r * NSEG + (tid + 1)];
    ws[V_OFF + ((size_t)b * NLBL + tid) * NBXV + bx] = v;
  }
}

// unchanged from R8
__global__ __launch_bounds__(256)
void k_final(float* __restrict__ ws) {
  __shared__ float s_m[NLBL * 33];
  __shared__ float s_c[NLBL];
  __shared__ float s_vs[NLBL];
  __shared__ int   s_p[NLBL];
  __shared__ float s_red[4];
  const int b = blockIdx.x, tid = threadIdx.x;
  const int wave = tid >> 6, lane = tid & 63;

  if (tid < 160) {
    const int g = tid >> 3, j = tid & 7;
    const float4* v4 = (const float4*)(ws + V_OFF + ((size_t)b * NLBL + g) * NBXV + j * 16);
    float s = 0.f;
    #pragma unroll
    for (int k = 0; k < 4; ++k) { const float4 v = v4[k]; s += v.x + v.y + v.z + v.w; }
    s += __shfl_xor(s, 1, 64); s += __shfl_xor(s, 2, 64); s += __shfl_xor(s, 4, 64);
    if (j == 0) s_vs[g] = s;
  }
  if (tid < NLBL) {
    const float c = ws[CN_OFF + b * NLBL + tid];
    s_c[tid] = c;
    s_p[tid] = (c > 0.f) ? 1 : 0;
  }
  if (tid < 160) {
    const float4 v = ((const float4*)(ws + M_OFF + (size_t)b * NLBL * DIM))[tid];
    const int flat = tid * 4, l = flat >> 5, d = flat & 31;
    float* dst = &s_m[l * 33 + d];
    dst[0] = v.x; dst[1] = v.y; dst[2] = v.z; dst[3] = v.w;
  }
  __syncthreads();

  float dl = 0.f;
  for (int p = tid; p < NLBL * NLBL; p += 256) {
    const int i = p / NLBL, j = p - (p / NLBL) * NLBL;
    if (i != j && s_p[i] && s_p[j]) {
      float sq = 0.f;
      #pragma unroll
      for (int d = 0; d < DIM; ++d) {
        const float t = s_m[i * 33 + d] - s_m[j * 33 + d];
        sq += t * t;
      }
      const float r = DD - sqrtf(sq);
      if (r > 0.f) dl += r * r;
    }
  }
  #pragma unroll
  for (int off = 32; off; off >>= 1) dl += __shfl_xor(dl, off, 64);
  if (lane == 0) s_red[wave] = dl;
  __syncthreads();
  if (tid == 0) {
    const float dsum = s_red[0] + s_red[1] + s_red[2] + s_red[3];
    float nl = 0.f, var = 0.f;
    for (int l = 0; l < NLBL; ++l)
      if (s_p[l]) { nl += 1.f; var += s_vs[l] / s_c[l]; }
    ws[PB_OFF + b * 2]     = (nl > 0.f) ? var / nl : 0.f;
    ws[PB_OFF + b * 2 + 1] = (nl > 1.f) ? dsum / fmaxf(nl * (nl - 1.f), 1.f) * 0.5f : 0.f;
  }
}

__global__ __launch_bounds__(64)
void k_out(const float* __restrict__ ws, float* __restrict__ out) {
  const int tid = threadIdx.x;
  float v = 0.f, d = 0.f;
  if (tid < BATCH) {
    v = ws[PB_OFF + tid * 2];
    d = ws[PB_OFF + tid * 2 + 1];
  }
  #pragma unroll
  for (int off = 4; off; off >>= 1) { v += __shfl_xor(v, off, 64); d += __shfl_xor(d, off, 64); }
  if (tid == 0) {
    out[0] = v / (float)BATCH;
    out[1] = d / (float)BATCH;
    out[2] = 0.f;
  }
}

extern "C" void kernel_launch(void* const* d_in, const int* in_sizes, int n_in,
                              void* d_out, int out_size, void* d_ws, size_t ws_size,
                              hipStream_t stream) {
  const float* emb = (const float*)d_in[0];
  const int*   seg = (const int*)d_in[1];
  float* out = (float*)d_out;
  float* ws  = (float*)d_ws;
  const int N = in_sizes[1] / BATCH;   // 65536

  k_moments<<<dim3(NS, BATCH), 256, 0, stream>>>(emb, seg, ws);
  k_means  <<<dim3(BATCH), 256, 0, stream>>>(ws);
  k_var    <<<dim3(NBXV, BATCH), 256, 0, stream>>>(emb, seg, ws, N);
  k_final  <<<dim3(BATCH), 256, 0, stream>>>(ws);
  k_out    <<<1, 64, 0, stream>>>(ws, out);
}

// Round 11
// 48.041 us; speedup vs baseline: 2.7513x; 1.2020x over previous
//
#include <hip/hip_runtime.h>
#include <hip/hip_cooperative_groups.h>
namespace cg = cooperative_groups;

#define NSEG 21
#define NLBL 20
#define DIM  32
#define NS   128     // pixel slots (blocks.x); 512 px each
#define NREP 16
#define DV   0.5f
#define DD   3.0f
#define BATCH 8
#define N_PIX 65536

using short8 = __attribute__((ext_vector_type(8))) short;
using f32x4  = __attribute__((ext_vector_type(4))) float;

// ws float layout (fully overwritten every call):
#define P_OFF  0         // part  [B][32][20][NS]   655360
#define C2_OFF 655360    // cpart [B][20][NS]        20480
#define M_OFF  675840    // means [B][l*32+d]         5120
#define CN_OFF 680960    // cnt   [B][20]              160
#define V_OFF  681120    // vpart [B][20][NS]        20480
#define PB_OFF 701600    // pb    [B][2]                16

__device__ __forceinline__ short bf16rne(float f) {
  const unsigned u = __builtin_bit_cast(unsigned, f);
  return (short)((u + 0x7FFFu + ((u >> 16) & 1u)) >> 16);
}

// ---- Stage A: MFMA segment sums+counts, 512 px/block. lred = 1536 floats. ----
__device__ __forceinline__ void momentsBody(const float* __restrict__ emb,
                                            const int* __restrict__ seg,
                                            float* __restrict__ ws,
                                            float* lred, int bx, int b, int tid) {
  const int wv = tid >> 6, lane = tid & 63;
  const int lr = lane & 15, lg = lane >> 4;
  const float* rowA0 = emb + ((size_t)b * DIM + lr) * N_PIX;
  const float* rowA1 = rowA0 + (size_t)16 * N_PIX;
  const int*   segb  = seg + (size_t)b * N_PIX;

  f32x4 s00 = {0,0,0,0}, s01 = {0,0,0,0}, s10 = {0,0,0,0}, s11 = {0,0,0,0};
  f32x4 c0  = {0,0,0,0}, c1  = {0,0,0,0};
  short8 ones;
  #pragma unroll
  for (int j = 0; j < 8; ++j) ones[j] = (short)0x3F80;

  const int nbase = bx * 512 + wv * 32;
  #pragma unroll 2
  for (int t = 0; t < 4; ++t) {
    const int koff = nbase + t * 128 + lg * 8;
    const float4 a00 = *(const float4*)(rowA0 + koff);
    const float4 a01 = *(const float4*)(rowA0 + koff + 4);
    const float4 a10 = *(const float4*)(rowA1 + koff);
    const float4 a11 = *(const float4*)(rowA1 + koff + 4);
    const int4   g0  = *(const int4*)(segb + koff);
    const int4   g1  = *(const int4*)(segb + koff + 4);

    short8 fa0, fa1, fb0, fb1;
    fa0[0] = bf16rne(a00.x); fa0[1] = bf16rne(a00.y);
    fa0[2] = bf16rne(a00.z); fa0[3] = bf16rne(a00.w);
    fa0[4] = bf16rne(a01.x); fa0[5] = bf16rne(a01.y);
    fa0[6] = bf16rne(a01.z); fa0[7] = bf16rne(a01.w);
    fa1[0] = bf16rne(a10.x); fa1[1] = bf16rne(a10.y);
    fa1[2] = bf16rne(a10.z); fa1[3] = bf16rne(a10.w);
    fa1[4] = bf16rne(a11.x); fa1[5] = bf16rne(a11.y);
    fa1[6] = bf16rne(a11.z); fa1[7] = bf16rne(a11.w);
    const int lab0 = lr + 1, lab1 = lr + 17;
    fb0[0] = (g0.x == lab0) ? (short)0x3F80 : (short)0;
    fb0[1] = (g0.y == lab0) ? (short)0x3F80 : (short)0;
    fb0[2] = (g0.z == lab0) ? (short)0x3F80 : (short)0;
    fb0[3] = (g0.w == lab0) ? (short)0x3F80 : (short)0;
    fb0[4] = (g1.x == lab0) ? (short)0x3F80 : (short)0;
    fb0[5] = (g1.y == lab0) ? (short)0x3F80 : (short)0;
    fb0[6] = (g1.z == lab0) ? (short)0x3F80 : (short)0;
    fb0[7] = (g1.w == lab0) ? (short)0x3F80 : (short)0;
    fb1[0] = (g0.x == lab1) ? (short)0x3F80 : (short)0;
    fb1[1] = (g0.y == lab1) ? (short)0x3F80 : (short)0;
    fb1[2] = (g0.z == lab1) ? (short)0x3F80 : (short)0;
    fb1[3] = (g0.w == lab1) ? (short)0x3F80 : (short)0;
    fb1[4] = (g1.x == lab1) ? (short)0x3F80 : (short)0;
    fb1[5] = (g1.y == lab1) ? (short)0x3F80 : (short)0;
    fb1[6] = (g1.z == lab1) ? (short)0x3F80 : (short)0;
    fb1[7] = (g1.w == lab1) ? (short)0x3F80 : (short)0;

    s00 = __builtin_amdgcn_mfma_f32_16x16x32_bf16(fa0, fb0, s00, 0, 0, 0);
    s01 = __builtin_amdgcn_mfma_f32_16x16x32_bf16(fa0, fb1, s01, 0, 0, 0);
    s10 = __builtin_amdgcn_mfma_f32_16x16x32_bf16(fa1, fb0, s10, 0, 0, 0);
    s11 = __builtin_amdgcn_mfma_f32_16x16x32_bf16(fa1, fb1, s11, 0, 0, 0);
    c0  = __builtin_amdgcn_mfma_f32_16x16x32_bf16(ones, fb0, c0, 0, 0, 0);
    c1  = __builtin_amdgcn_mfma_f32_16x16x32_bf16(ones, fb1, c1, 0, 0, 0);
  }

  // sequential per-wave accumulation into lred[1536] (no LDS atomics)
  float vals[24];
  #pragma unroll
  for (int r = 0; r < 4; ++r) {
    vals[0 * 4 + r] = s00[r]; vals[1 * 4 + r] = s01[r];
    vals[2 * 4 + r] = s10[r]; vals[3 * 4 + r] = s11[r];
    vals[4 * 4 + r] = c0[r];  vals[5 * 4 + r] = c1[r];
  }
  #pragma unroll
  for (int w = 0; w < 4; ++w) {
    if (wv == w) {
      float* base = lred + lane * 4;
      if (w == 0) {
        #pragma unroll
        for (int f = 0; f < 6; ++f) {
          #pragma unroll
          for (int r = 0; r < 4; ++r) base[f * 256 + r] = vals[f * 4 + r];
        }
      } else {
        #pragma unroll
        for (int f = 0; f < 6; ++f) {
          #pragma unroll
          for (int r = 0; r < 4; ++r) base[f * 256 + r] += vals[f * 4 + r];
        }
      }
    }
    __syncthreads();
  }
  // scatter to partials
  for (int i = tid; i < 1536; i += 256) {
    const float v = lred[i];
    const int f = i >> 8, ln = (i >> 2) & 63, r = i & 3;
    const int col = ln & 15, row = ((ln >> 4) << 2) | r;
    if (f < 4) {
      const int d = (f >> 1) * 16 + row;
      const int lcol = (f & 1) * 16 + col;
      if (lcol < NLBL)
        ws[P_OFF + (((size_t)(b * DIM + d) * NLBL) + lcol) * NS + bx] = v;
    } else {
      const int lcol = (f & 1) * 16 + col;
      if (row == 0 && lcol < NLBL)
        ws[C2_OFF + ((size_t)b * NLBL + lcol) * NS + bx] = v;
    }
  }
}

// ---- Stage B: canonical counts + means; bx8 in [0,8) handles 80 means. ----
__device__ __forceinline__ void meansBody(float* __restrict__ ws, float* s_c,
                                          int bx8, int b, int tid) {
  if (tid < NLBL) {
    const float4* cp = (const float4*)(ws + C2_OFF + ((size_t)b * NLBL + tid) * NS);
    float q0 = 0.f, q1 = 0.f, q2 = 0.f, q3 = 0.f;
    #pragma unroll
    for (int k = 0; k < NS / 4; k += 4) {
      const float4 v0 = cp[k], v1 = cp[k + 1], v2 = cp[k + 2], v3 = cp[k + 3];
      q0 += v0.x + v0.y + v0.z + v0.w;
      q1 += v1.x + v1.y + v1.z + v1.w;
      q2 += v2.x + v2.y + v2.z + v2.w;
      q3 += v3.x + v3.y + v3.z + v3.w;
    }
    const float c = q0 + q1 + q2 + q3;
    if (bx8 == 0) ws[CN_OFF + b * NLBL + tid] = c;
    s_c[tid] = fmaxf(c, 1.f);
  }
  __syncthreads();
  if (tid < 80) {
    const int m = bx8 * 80 + tid;
    const int l = m >> 5;
    const int d = m & 31;
    const float4* pp = (const float4*)(ws + P_OFF + (((size_t)(b * DIM + d) * NLBL) + l) * NS);
    float q0 = 0.f, q1 = 0.f, q2 = 0.f, q3 = 0.f;
    #pragma unroll
    for (int k = 0; k < NS / 4; k += 4) {
      const float4 v0 = pp[k], v1 = pp[k + 1], v2 = pp[k + 2], v3 = pp[k + 3];
      q0 += v0.x + v0.y + v0.z + v0.w;
      q1 += v1.x + v1.y + v1.z + v1.w;
      q2 += v2.x + v2.y + v2.z + v2.w;
      q3 += v3.x + v3.y + v3.z + v3.w;
    }
    ws[M_OFF + (size_t)b * NLBL * DIM + m] = (q0 + q1 + q2 + q3) / s_c[l];
  }
}

// ---- Stage C: variance pass, 512 px/block, 2 px/thread. ----
__device__ __forceinline__ void varBody(const float* __restrict__ emb,
                                        const int* __restrict__ seg,
                                        float* __restrict__ ws,
                                        float* s_m, float* s_v,
                                        int bx, int b, int tid) {
  for (int i = tid; i < NSEG * 33; i += 256) s_m[i] = 0.f;
  for (int i = tid; i < NREP * NSEG; i += 256) s_v[i] = 0.f;
  __syncthreads();
  if (tid < 160) {
    const float4 v = ((const float4*)(ws + M_OFF + (size_t)b * NLBL * DIM))[tid];
    const int flat = tid * 4, l = flat >> 5, d = flat & 31;
    float* dst = &s_m[(l + 1) * 33 + d];
    dst[0] = v.x; dst[1] = v.y; dst[2] = v.z; dst[3] = v.w;
  }
  __syncthreads();

  const int n0 = bx * 512;
  const int2 sl = ((const int2*)(seg + (size_t)b * N_PIX + n0))[tid];
  const float2* e2 = (const float2*)(emb + (size_t)b * DIM * N_PIX + n0) + tid;
  const int mx = sl.x * 33, my = sl.y * 33;
  float q0 = 0.f, q1 = 0.f;
  #pragma unroll 8
  for (int d = 0; d < DIM; ++d) {
    const float2 e = e2[d * (N_PIX / 2)];
    float t;
    t = e.x - s_m[mx + d]; q0 += t * t;
    t = e.y - s_m[my + d]; q1 += t * t;
  }
  const int rb = (tid & (NREP - 1)) * NSEG;
  if (sl.x > 0) { const float r = sqrtf(q0) - DV; if (r > 0.f) atomicAdd(&s_v[rb + sl.x], r * r); }
  if (sl.y > 0) { const float r = sqrtf(q1) - DV; if (r > 0.f) atomicAdd(&s_v[rb + sl.y], r * r); }
  __syncthreads();
  if (tid < NLBL) {
    float v = 0.f;
    #pragma unroll
    for (int r = 0; r < NREP; ++r) v += s_v[r * NSEG + (tid + 1)];
    ws[V_OFF + ((size_t)b * NLBL + tid) * NS + bx] = v;
  }
}

// ---- Stage D: per-batch finalize (self-contained; reloads means). ----
__device__ __forceinline__ void finalBody(float* __restrict__ ws,
                                          float* s_m, float* s_c, float* s_vs,
                                          int* s_p, float* s_red, int b, int tid) {
  const int wv = tid >> 6, lane = tid & 63;
  if (tid < 160) {
    const int g = tid >> 3, j = tid & 7;
    const float4* v4 = (const float4*)(ws + V_OFF + ((size_t)b * NLBL + g) * NS + j * 16);
    float s = 0.f;
    #pragma unroll
    for (int k = 0; k < 4; ++k) { const float4 v = v4[k]; s += v.x + v.y + v.z + v.w; }
    s += __shfl_xor(s, 1, 64); s += __shfl_xor(s, 2, 64); s += __shfl_xor(s, 4, 64);
    if (j == 0) s_vs[g] = s;
  }
  if (tid < NLBL) {
    const float c = ws[CN_OFF + b * NLBL + tid];
    s_c[tid] = c;
    s_p[tid] = (c > 0.f) ? 1 : 0;
  }
  if (tid < 160) {
    const float4 v = ((const float4*)(ws + M_OFF + (size_t)b * NLBL * DIM))[tid];
    const int flat = tid * 4, l = flat >> 5, d = flat & 31;
    float* dst = &s_m[l * 33 + d];
    dst[0] = v.x; dst[1] = v.y; dst[2] = v.z; dst[3] = v.w;
  }
  __syncthreads();

  float dl = 0.f;
  for (int p = tid; p < NLBL * NLBL; p += 256) {
    const int i = p / NLBL, j = p - (p / NLBL) * NLBL;
    if (i != j && s_p[i] && s_p[j]) {
      float sq = 0.f;
      #pragma unroll
      for (int d = 0; d < DIM; ++d) {
        const float t = s_m[i * 33 + d] - s_m[j * 33 + d];
        sq += t * t;
      }
      const float r = DD - sqrtf(sq);
      if (r > 0.f) dl += r * r;
    }
  }
  #pragma unroll
  for (int off = 32; off; off >>= 1) dl += __shfl_xor(dl, off, 64);
  if (lane == 0) s_red[wv] = dl;
  __syncthreads();
  if (tid == 0) {
    const float dsum = s_red[0] + s_red[1] + s_red[2] + s_red[3];
    float nl = 0.f, var = 0.f;
    for (int l = 0; l < NLBL; ++l)
      if (s_p[l]) { nl += 1.f; var += s_vs[l] / s_c[l]; }
    ws[PB_OFF + b * 2]     = (nl > 0.f) ? var / nl : 0.f;
    ws[PB_OFF + b * 2 + 1] = (nl > 1.f) ? dsum / fmaxf(nl * (nl - 1.f), 1.f) * 0.5f : 0.f;
  }
}

__device__ __forceinline__ void outBody(const float* __restrict__ ws,
                                        float* __restrict__ out, int tid) {
  if (tid < 64) {
    float v = 0.f, d = 0.f;
    if (tid < BATCH) {
      v = ws[PB_OFF + tid * 2];
      d = ws[PB_OFF + tid * 2 + 1];
    }
    #pragma unroll
    for (int off = 4; off; off >>= 1) { v += __shfl_xor(v, off, 64); d += __shfl_xor(d, off, 64); }
    if (tid == 0) {
      out[0] = v / (float)BATCH;
      out[1] = d / (float)BATCH;
      out[2] = 0.f;
    }
  }
}

// ---------------- fused cooperative kernel (LDS ~10.5 KB) ----------------
__global__ __launch_bounds__(256, 4)
void k_fused(const float* __restrict__ emb, const int* __restrict__ seg,
             float* __restrict__ ws, float* __restrict__ out) {
  __shared__ float lred[1536];
  __shared__ float s_m[NSEG * 33];
  __shared__ float s_v[NREP * NSEG];
  __shared__ float s_c[NLBL];
  __shared__ float s_vs[NLBL];
  __shared__ int   s_p[NLBL];
  __shared__ float s_red[4];
  cg::grid_group gg = cg::this_grid();
  const int tid = threadIdx.x, bx = blockIdx.x, b = blockIdx.y;

  momentsBody(emb, seg, ws, lred, bx, b, tid);
  gg.sync();
  if (bx < 8) meansBody(ws, s_c, bx, b, tid);
  gg.sync();
  varBody(emb, seg, ws, s_m, s_v, bx, b, tid);
  gg.sync();
  if (bx == 0) finalBody(ws, s_m, s_c, s_vs, s_p, s_red, b, tid);
  gg.sync();
  if (bx == 0 && b == 0) outBody(ws, out, tid);
}

// ---------------- fallback discrete pipeline (same bodies) ----------------
__global__ __launch_bounds__(256)
void k_moments(const float* __restrict__ emb, const int* __restrict__ seg,
               float* __restrict__ ws) {
  __shared__ float lred[1536];
  momentsBody(emb, seg, ws, lred, blockIdx.x, blockIdx.y, threadIdx.x);
}
__global__ __launch_bounds__(256)
void k_means(float* __restrict__ ws) {
  __shared__ float s_c[NLBL];
  meansBody(ws, s_c, blockIdx.x, blockIdx.y, threadIdx.x);
}
__global__ __launch_bounds__(256)
void k_var(const float* __restrict__ emb, const int* __restrict__ seg,
           float* __restrict__ ws) {
  __shared__ float s_m[NSEG * 33];
  __shared__ float s_v[NREP * NSEG];
  varBody(emb, seg, ws, s_m, s_v, blockIdx.x, blockIdx.y, threadIdx.x);
}
__global__ __launch_bounds__(256)
void k_final(float* __restrict__ ws) {
  __shared__ float s_m[NLBL * 33];
  __shared__ float s_c[NLBL];
  __shared__ float s_vs[NLBL];
  __shared__ int   s_p[NLBL];
  __shared__ float s_red[4];
  finalBody(ws, s_m, s_c, s_vs, s_p, s_red, blockIdx.x, threadIdx.x);
}
__global__ __launch_bounds__(64)
void k_out(const float* __restrict__ ws, float* __restrict__ out) {
  outBody(ws, out, threadIdx.x);
}

extern "C" void kernel_launch(void* const* d_in, const int* in_sizes, int n_in,
                              void* d_out, int out_size, void* d_ws, size_t ws_size,
                              hipStream_t stream) {
  const float* emb = (const float*)d_in[0];
  const int*   seg = (const int*)d_in[1];
  float* out = (float*)d_out;
  float* ws  = (float*)d_ws;

  // Cooperative path only if the whole grid is co-resident (MI355X: 256 CUs).
  int maxB = 0;
  bool coop = false;
  if (hipOccupancyMaxActiveBlocksPerMultiprocessor(&maxB, (const void*)k_fused, 256, 0)
        == hipSuccess)
    coop = ((long)maxB * 256 >= (long)NS * BATCH);
  if (coop) {
    void* args[] = {(void*)&emb, (void*)&seg, (void*)&ws, (void*)&out};
    if (hipLaunchCooperativeKernel((const void*)k_fused, dim3(NS, BATCH), dim3(256),
                                   args, 0, stream) == hipSuccess)
      return;
  }
  // fallback: discrete pipeline (identical math)
  k_moments<<<dim3(NS, BATCH), 256, 0, stream>>>(emb, seg, ws);
  k_means  <<<dim3(8, BATCH), 256, 0, stream>>>(ws);
  k_var    <<<dim3(NS, BATCH), 256, 0, stream>>>(emb, seg, ws);
  k_final  <<<dim3(BATCH), 256, 0, stream>>>(ws);
  k_out    <<<1, 64, 0, stream>>>(ws, out);
}

// Round 12
// 43.193 us; speedup vs baseline: 3.0601x; 1.1122x over previous
//
#include <hip/hip_runtime.h>
#include <hip/hip_cooperative_groups.h>
namespace cg = cooperative_groups;

#define NSEG 21
#define NLBL 20
#define DIM  32
#define NS   64      // slots per batch; 1024 px each
#define NREP 16
#define DV   0.5f
#define DD   3.0f
#define BATCH 8
#define N_PIX 65536
#define SMS  36      // s_m row stride (16B-aligned rows for b128 mean loads)
#define DYNB (128*512 + 1024)   // LDS tile 64KB (bf16) + 1KB labels

using short8 = __attribute__((ext_vector_type(8))) short;
using f32x4  = __attribute__((ext_vector_type(4))) float;

// ws float layout (fully overwritten every call):
#define P_OFF  0                            // part  [B][32][20][NS]  327680
#define C2_OFF (BATCH*DIM*NLBL*NS)          // cpart [B][20][NS]       10240
#define M_OFF  (C2_OFF + BATCH*NLBL*NS)     // means [B][640]           5120
#define CN_OFF (M_OFF + BATCH*NLBL*DIM)     // cnt   [B][20]             160
#define V_OFF  (CN_OFF + BATCH*NLBL)        // vpart [B][20][NS]       10240
#define PB_OFF (V_OFF + BATCH*NLBL*NS)      // pb    [B][2]               16

__device__ __forceinline__ short bf16rne(float f) {
  const unsigned u = __builtin_bit_cast(unsigned, f);
  return (short)((u + 0x7FFFu + ((u >> 16) & 1u)) >> 16);
}

// ---- Stage A: MFMA segment sums+counts, 1024 px/block; also stashes the
// bf16 pixel tile + labels in LDS (tile[o][d^(o&7)][8px], conflict-free writes).
__device__ __forceinline__ void momentsBody(const float* __restrict__ emb,
                                            const int* __restrict__ seg,
                                            float* __restrict__ ws,
                                            float* lred, ushort* tile,
                                            unsigned char* segt,
                                            int bx, int b, int tid) {
  const int wv = tid >> 6, lane = tid & 63;
  const int lr = lane & 15, lg = lane >> 4;
  const float* rowA0 = emb + ((size_t)b * DIM + lr) * N_PIX;
  const float* rowA1 = rowA0 + (size_t)16 * N_PIX;
  const int*   segb  = seg + (size_t)b * N_PIX;

  f32x4 s00 = {0,0,0,0}, s01 = {0,0,0,0}, s10 = {0,0,0,0}, s11 = {0,0,0,0};
  f32x4 c0  = {0,0,0,0}, c1  = {0,0,0,0};
  short8 ones;
  #pragma unroll
  for (int j = 0; j < 8; ++j) ones[j] = (short)0x3F80;

  #pragma unroll 2
  for (int t = 0; t < 8; ++t) {
    const int kl = wv * 256 + t * 32 + lg * 8;   // local px
    const int koff = bx * 1024 + kl;
    const float4 a00 = *(const float4*)(rowA0 + koff);
    const float4 a01 = *(const float4*)(rowA0 + koff + 4);
    const float4 a10 = *(const float4*)(rowA1 + koff);
    const float4 a11 = *(const float4*)(rowA1 + koff + 4);
    const int4   g0  = *(const int4*)(segb + koff);
    const int4   g1  = *(const int4*)(segb + koff + 4);

    short8 fa0, fa1, fb0, fb1;
    fa0[0] = bf16rne(a00.x); fa0[1] = bf16rne(a00.y);
    fa0[2] = bf16rne(a00.z); fa0[3] = bf16rne(a00.w);
    fa0[4] = bf16rne(a01.x); fa0[5] = bf16rne(a01.y);
    fa0[6] = bf16rne(a01.z); fa0[7] = bf16rne(a01.w);
    fa1[0] = bf16rne(a10.x); fa1[1] = bf16rne(a10.y);
    fa1[2] = bf16rne(a10.z); fa1[3] = bf16rne(a10.w);
    fa1[4] = bf16rne(a11.x); fa1[5] = bf16rne(a11.y);
    fa1[6] = bf16rne(a11.z); fa1[7] = bf16rne(a11.w);
    const int lab0 = lr + 1, lab1 = lr + 17;
    fb0[0] = (g0.x == lab0) ? (short)0x3F80 : (short)0;
    fb0[1] = (g0.y == lab0) ? (short)0x3F80 : (short)0;
    fb0[2] = (g0.z == lab0) ? (short)0x3F80 : (short)0;
    fb0[3] = (g0.w == lab0) ? (short)0x3F80 : (short)0;
    fb0[4] = (g1.x == lab0) ? (short)0x3F80 : (short)0;
    fb0[5] = (g1.y == lab0) ? (short)0x3F80 : (short)0;
    fb0[6] = (g1.z == lab0) ? (short)0x3F80 : (short)0;
    fb0[7] = (g1.w == lab0) ? (short)0x3F80 : (short)0;
    fb1[0] = (g0.x == lab1) ? (short)0x3F80 : (short)0;
    fb1[1] = (g0.y == lab1) ? (short)0x3F80 : (short)0;
    fb1[2] = (g0.z == lab1) ? (short)0x3F80 : (short)0;
    fb1[3] = (g0.w == lab1) ? (short)0x3F80 : (short)0;
    fb1[4] = (g1.x == lab1) ? (short)0x3F80 : (short)0;
    fb1[5] = (g1.y == lab1) ? (short)0x3F80 : (short)0;
    fb1[6] = (g1.z == lab1) ? (short)0x3F80 : (short)0;
    fb1[7] = (g1.w == lab1) ? (short)0x3F80 : (short)0;

    // stash tile (swizzled row: d ^ (o&7)); writes are 2-way -> conflict-free
    const int o = kl >> 3, om = o & 7;
    *(short8*)&tile[o * 256 + ((lr ^ om) << 3)] = fa0;
    *(short8*)&tile[o * 256 + (((lr ^ om) + 16) << 3)] = fa1;
    if (lr == 0) {
      unsigned long long pk =
          (unsigned long long)(g0.x & 255)        | ((unsigned long long)(g0.y & 255) << 8) |
          ((unsigned long long)(g0.z & 255) << 16) | ((unsigned long long)(g0.w & 255) << 24) |
          ((unsigned long long)(g1.x & 255) << 32) | ((unsigned long long)(g1.y & 255) << 40) |
          ((unsigned long long)(g1.z & 255) << 48) | ((unsigned long long)(g1.w & 255) << 56);
      *(unsigned long long*)&segt[o * 8] = pk;
    }

    s00 = __builtin_amdgcn_mfma_f32_16x16x32_bf16(fa0, fb0, s00, 0, 0, 0);
    s01 = __builtin_amdgcn_mfma_f32_16x16x32_bf16(fa0, fb1, s01, 0, 0, 0);
    s10 = __builtin_amdgcn_mfma_f32_16x16x32_bf16(fa1, fb0, s10, 0, 0, 0);
    s11 = __builtin_amdgcn_mfma_f32_16x16x32_bf16(fa1, fb1, s11, 0, 0, 0);
    c0  = __builtin_amdgcn_mfma_f32_16x16x32_bf16(ones, fb0, c0, 0, 0, 0);
    c1  = __builtin_amdgcn_mfma_f32_16x16x32_bf16(ones, fb1, c1, 0, 0, 0);
  }

  // sequential per-wave accumulation into lred[1536] (no LDS atomics)
  float vals[24];
  #pragma unroll
  for (int r = 0; r < 4; ++r) {
    vals[0 * 4 + r] = s00[r]; vals[1 * 4 + r] = s01[r];
    vals[2 * 4 + r] = s10[r]; vals[3 * 4 + r] = s11[r];
    vals[4 * 4 + r] = c0[r];  vals[5 * 4 + r] = c1[r];
  }
  #pragma unroll
  for (int w = 0; w < 4; ++w) {
    if (wv == w) {
      float* base = lred + lane * 4;
      if (w == 0) {
        #pragma unroll
        for (int f = 0; f < 6; ++f)
          #pragma unroll
          for (int r = 0; r < 4; ++r) base[f * 256 + r] = vals[f * 4 + r];
      } else {
        #pragma unroll
        for (int f = 0; f < 6; ++f)
          #pragma unroll
          for (int r = 0; r < 4; ++r) base[f * 256 + r] += vals[f * 4 + r];
      }
    }
    __syncthreads();
  }
  for (int i = tid; i < 1536; i += 256) {
    const float v = lred[i];
    const int f = i >> 8, ln = (i >> 2) & 63, r = i & 3;
    const int col = ln & 15, row = ((ln >> 4) << 2) | r;
    if (f < 4) {
      const int d = (f >> 1) * 16 + row;
      const int lcol = (f & 1) * 16 + col;
      if (lcol < NLBL)
        ws[P_OFF + (((size_t)(b * DIM + d) * NLBL) + lcol) * NS + bx] = v;
    } else {
      const int lcol = (f & 1) * 16 + col;
      if (row == 0 && lcol < NLBL)
        ws[C2_OFF + ((size_t)b * NLBL + lcol) * NS + bx] = v;
    }
  }
}

// ---- Stage B: canonical counts + means; 8 blocks per batch. ----
__device__ __forceinline__ void meansBody(float* __restrict__ ws, float* s_c,
                                          int bx8, int b, int tid) {
  if (tid < NLBL) {
    const float4* cp = (const float4*)(ws + C2_OFF + ((size_t)b * NLBL + tid) * NS);
    float q0 = 0.f, q1 = 0.f, q2 = 0.f, q3 = 0.f;
    #pragma unroll
    for (int k = 0; k < NS / 4; k += 4) {
      const float4 v0 = cp[k], v1 = cp[k + 1], v2 = cp[k + 2], v3 = cp[k + 3];
      q0 += v0.x + v0.y + v0.z + v0.w;
      q1 += v1.x + v1.y + v1.z + v1.w;
      q2 += v2.x + v2.y + v2.z + v2.w;
      q3 += v3.x + v3.y + v3.z + v3.w;
    }
    const float c = q0 + q1 + q2 + q3;
    if (bx8 == 0) ws[CN_OFF + b * NLBL + tid] = c;
    s_c[tid] = fmaxf(c, 1.f);
  }
  __syncthreads();
  if (tid < 80) {
    const int m = bx8 * 80 + tid;
    const int l = m >> 5, d = m & 31;
    const float4* pp = (const float4*)(ws + P_OFF + (((size_t)(b * DIM + d) * NLBL) + l) * NS);
    float q0 = 0.f, q1 = 0.f, q2 = 0.f, q3 = 0.f;
    #pragma unroll
    for (int k = 0; k < NS / 4; k += 4) {
      const float4 v0 = pp[k], v1 = pp[k + 1], v2 = pp[k + 2], v3 = pp[k + 3];
      q0 += v0.x + v0.y + v0.z + v0.w;
      q1 += v1.x + v1.y + v1.z + v1.w;
      q2 += v2.x + v2.y + v2.z + v2.w;
      q3 += v3.x + v3.y + v3.z + v3.w;
    }
    ws[M_OFF + (size_t)b * NLBL * DIM + m] = (q0 + q1 + q2 + q3) / s_c[l];
  }
}

// ---- shared means loader: rows (label) at stride SMS, row 0 = zeros ----
__device__ __forceinline__ void loadMeans(const float* __restrict__ ws,
                                          float* s_m, int b, int tid) {
  for (int i = tid; i < NSEG * SMS; i += 256) s_m[i] = 0.f;
  __syncthreads();
  if (tid < 160) {
    const float4 v = ((const float4*)(ws + M_OFF + (size_t)b * NLBL * DIM))[tid];
    const int flat = tid * 4, l = flat >> 5, d = flat & 31;
    float* dst = &s_m[(l + 1) * SMS + d];
    dst[0] = v.x; dst[1] = v.y; dst[2] = v.z; dst[3] = v.w;
  }
}

// ---- Stage D: per-batch finalize. ----
__device__ __forceinline__ void finalBody(float* __restrict__ ws,
                                          float* s_m, float* s_c, float* s_vs,
                                          int* s_p, float* s_red, int b, int tid) {
  const int wv = tid >> 6, lane = tid & 63;
  if (tid < 160) {
    const int g = tid >> 3, j = tid & 7;
    const float4* v4 = (const float4*)(ws + V_OFF + ((size_t)b * NLBL + g) * NS + j * 8);
    const float4 a = v4[0], c = v4[1];
    float s = a.x + a.y + a.z + a.w + c.x + c.y + c.z + c.w;
    s += __shfl_xor(s, 1, 64); s += __shfl_xor(s, 2, 64); s += __shfl_xor(s, 4, 64);
    if (j == 0) s_vs[g] = s;
  }
  if (tid < NLBL) {
    const float c = ws[CN_OFF + b * NLBL + tid];
    s_c[tid] = c;
    s_p[tid] = (c > 0.f) ? 1 : 0;
  }
  __syncthreads();
  loadMeans(ws, s_m, b, tid);
  __syncthreads();

  float dl = 0.f;
  for (int p = tid; p < NLBL * NLBL; p += 256) {
    const int i = p / NLBL, j = p - (p / NLBL) * NLBL;
    if (i != j && s_p[i] && s_p[j]) {
      float sq = 0.f;
      #pragma unroll
      for (int d = 0; d < DIM; ++d) {
        const float t = s_m[(i + 1) * SMS + d] - s_m[(j + 1) * SMS + d];
        sq += t * t;
      }
      const float r = DD - sqrtf(sq);
      if (r > 0.f) dl += r * r;
    }
  }
  #pragma unroll
  for (int off = 32; off; off >>= 1) dl += __shfl_xor(dl, off, 64);
  if (lane == 0) s_red[wv] = dl;
  __syncthreads();
  if (tid == 0) {
    const float dsum = s_red[0] + s_red[1] + s_red[2] + s_red[3];
    float nl = 0.f, var = 0.f;
    for (int l = 0; l < NLBL; ++l)
      if (s_p[l]) { nl += 1.f; var += s_vs[l] / s_c[l]; }
    ws[PB_OFF + b * 2]     = (nl > 0.f) ? var / nl : 0.f;
    ws[PB_OFF + b * 2 + 1] = (nl > 1.f) ? dsum / fmaxf(nl * (nl - 1.f), 1.f) * 0.5f : 0.f;
  }
}

__device__ __forceinline__ void outBody(const float* __restrict__ ws,
                                        float* __restrict__ out, int tid) {
  if (tid < 64) {
    float v = 0.f, d = 0.f;
    if (tid < BATCH) {
      v = ws[PB_OFF + tid * 2];
      d = ws[PB_OFF + tid * 2 + 1];
    }
    #pragma unroll
    for (int off = 4; off; off >>= 1) { v += __shfl_xor(v, off, 64); d += __shfl_xor(d, off, 64); }
    if (tid == 0) {
      out[0] = v / (float)BATCH;
      out[1] = d / (float)BATCH;
      out[2] = 0.f;
    }
  }
}

// ---------------- fused cooperative kernel ----------------
__global__ __launch_bounds__(256, 2)
void k_fused(const float* __restrict__ emb, const int* __restrict__ seg,
             float* __restrict__ ws, float* __restrict__ out) {
  extern __shared__ __align__(16) char dynls[];
  ushort* tile = (ushort*)dynls;                       // 64KB
  unsigned char* segt = (unsigned char*)(dynls + 65536); // 1KB
  __shared__ __align__(16) float lred[1536];
  __shared__ __align__(16) float s_m[NSEG * SMS];
  __shared__ float s_v[NREP * NSEG];
  __shared__ float s_c[NLBL];
  __shared__ float s_vs[NLBL];
  __shared__ int   s_p[NLBL];
  __shared__ float s_red[4];
  cg::grid_group gg = cg::this_grid();
  const int tid = threadIdx.x, bx = blockIdx.x, b = blockIdx.y;

  momentsBody(emb, seg, ws, lred, tile, segt, bx, b, tid);
  gg.sync();
  if (bx < 8) meansBody(ws, s_c, bx, b, tid);
  gg.sync();

  // ---- Stage C: variance pass from the resident LDS tile (no global reads) ----
  for (int i = tid; i < NREP * NSEG; i += 256) s_v[i] = 0.f;
  loadMeans(ws, s_m, b, tid);
  __syncthreads();
  {
    const int px0 = tid * 4;
    const int o = px0 >> 3, om = o & 7, p8 = px0 & 7;
    const int la0 = segt[px0], la1 = segt[px0 + 1], la2 = segt[px0 + 2], la3 = segt[px0 + 3];
    float q0 = 0.f, q1 = 0.f, q2 = 0.f, q3 = 0.f;
    #pragma unroll
    for (int db = 0; db < 8; ++db) {
      const f32x4 m0 = *(const f32x4*)&s_m[la0 * SMS + db * 4];
      const f32x4 m1 = *(const f32x4*)&s_m[la1 * SMS + db * 4];
      const f32x4 m2 = *(const f32x4*)&s_m[la2 * SMS + db * 4];
      const f32x4 m3 = *(const f32x4*)&s_m[la3 * SMS + db * 4];
      #pragma unroll
      for (int dd = 0; dd < 4; ++dd) {
        const int d = db * 4 + dd;
        const ushort4 ev = *(const ushort4*)&tile[o * 256 + ((d ^ om) << 3) + p8];
        float t;
        t = __builtin_bit_cast(float, (unsigned)ev.x << 16) - m0[dd]; q0 += t * t;
        t = __builtin_bit_cast(float, (unsigned)ev.y << 16) - m1[dd]; q1 += t * t;
        t = __builtin_bit_cast(float, (unsigned)ev.z << 16) - m2[dd]; q2 += t * t;
        t = __builtin_bit_cast(float, (unsigned)ev.w << 16) - m3[dd]; q3 += t * t;
      }
    }
    const int rb = (tid & (NREP - 1)) * NSEG;
    if (la0 > 0) { const float r = sqrtf(q0) - DV; if (r > 0.f) atomicAdd(&s_v[rb + la0], r * r); }
    if (la1 > 0) { const float r = sqrtf(q1) - DV; if (r > 0.f) atomicAdd(&s_v[rb + la1], r * r); }
    if (la2 > 0) { const float r = sqrtf(q2) - DV; if (r > 0.f) atomicAdd(&s_v[rb + la2], r * r); }
    if (la3 > 0) { const float r = sqrtf(q3) - DV; if (r > 0.f) atomicAdd(&s_v[rb + la3], r * r); }
  }
  __syncthreads();
  if (tid < NLBL) {
    float v = 0.f;
    #pragma unroll
    for (int r = 0; r < NREP; ++r) v += s_v[r * NSEG + (tid + 1)];
    ws[V_OFF + ((size_t)b * NLBL + tid) * NS + bx] = v;
  }
  gg.sync();
  if (bx == 0) finalBody(ws, s_m, s_c, s_vs, s_p, s_red, b, tid);
  gg.sync();
  if (bx == 0 && b == 0) outBody(ws, out, tid);
}

// ---------------- fallback discrete pipeline ----------------
__global__ __launch_bounds__(256)
void k_moments(const float* __restrict__ emb, const int* __restrict__ seg,
               float* __restrict__ ws) {
  extern __shared__ __align__(16) char dynls[];
  ushort* tile = (ushort*)dynls;
  unsigned char* segt = (unsigned char*)(dynls + 65536);
  __shared__ __align__(16) float lred[1536];
  momentsBody(emb, seg, ws, lred, tile, segt, blockIdx.x, blockIdx.y, threadIdx.x);
}
__global__ __launch_bounds__(256)
void k_means(float* __restrict__ ws) {
  __shared__ float s_c[NLBL];
  meansBody(ws, s_c, blockIdx.x, blockIdx.y, threadIdx.x);
}
__global__ __launch_bounds__(256)
void k_varG(const float* __restrict__ emb, const int* __restrict__ seg,
            float* __restrict__ ws) {
  __shared__ __align__(16) float s_m[NSEG * SMS];
  __shared__ float s_v[NREP * NSEG];
  const int tid = threadIdx.x, bx = blockIdx.x, b = blockIdx.y;
  for (int i = tid; i < NREP * NSEG; i += 256) s_v[i] = 0.f;
  loadMeans(ws, s_m, b, tid);
  __syncthreads();
  const int n0 = bx * 1024 + tid * 4;
  const int4 sl = *(const int4*)(seg + (size_t)b * N_PIX + n0);
  const float4* e4 = (const float4*)(emb + (size_t)b * DIM * N_PIX + n0);
  float q0 = 0.f, q1 = 0.f, q2 = 0.f, q3 = 0.f;
  #pragma unroll 8
  for (int d = 0; d < DIM; ++d) {
    const float4 e = e4[d * (N_PIX / 4)];
    float t;
    t = e.x - s_m[sl.x * SMS + d]; q0 += t * t;
    t = e.y - s_m[sl.y * SMS + d]; q1 += t * t;
    t = e.z - s_m[sl.z * SMS + d]; q2 += t * t;
    t = e.w - s_m[sl.w * SMS + d]; q3 += t * t;
  }
  const int rb = (tid & (NREP - 1)) * NSEG;
  if (sl.x > 0) { const float r = sqrtf(q0) - DV; if (r > 0.f) atomicAdd(&s_v[rb + sl.x], r * r); }
  if (sl.y > 0) { const float r = sqrtf(q1) - DV; if (r > 0.f) atomicAdd(&s_v[rb + sl.y], r * r); }
  if (sl.z > 0) { const float r = sqrtf(q2) - DV; if (r > 0.f) atomicAdd(&s_v[rb + sl.z], r * r); }
  if (sl.w > 0) { const float r = sqrtf(q3) - DV; if (r > 0.f) atomicAdd(&s_v[rb + sl.w], r * r); }
  __syncthreads();
  if (tid < NLBL) {
    float v = 0.f;
    #pragma unroll
    for (int r = 0; r < NREP; ++r) v += s_v[r * NSEG + (tid + 1)];
    ws[V_OFF + ((size_t)b * NLBL + tid) * NS + bx] = v;
  }
}
__global__ __launch_bounds__(256)
void k_final(float* __restrict__ ws) {
  __shared__ __align__(16) float s_m[NSEG * SMS];
  __shared__ float s_c[NLBL];
  __shared__ float s_vs[NLBL];
  __shared__ int   s_p[NLBL];
  __shared__ float s_red[4];
  finalBody(ws, s_m, s_c, s_vs, s_p, s_red, blockIdx.x, threadIdx.x);
}
__global__ __launch_bounds__(64)
void k_out(const float* __restrict__ ws, float* __restrict__ out) {
  outBody(ws, out, threadIdx.x);
}

extern "C" void kernel_launch(void* const* d_in, const int* in_sizes, int n_in,
                              void* d_out, int out_size, void* d_ws, size_t ws_size,
                              hipStream_t stream) {
  const float* emb = (const float*)d_in[0];
  const int*   seg = (const int*)d_in[1];
  float* out = (float*)d_out;
  float* ws  = (float*)d_ws;

  int maxB = 0;
  bool coop = false;
  if (hipOccupancyMaxActiveBlocksPerMultiprocessor(&maxB, (const void*)k_fused, 256, DYNB)
        == hipSuccess)
    coop = ((long)maxB * 256 >= (long)NS * BATCH);
  if (coop) {
    void* args[] = {(void*)&emb, (void*)&seg, (void*)&ws, (void*)&out};
    if (hipLaunchCooperativeKernel((const void*)k_fused, dim3(NS, BATCH), dim3(256),
                                   args, DYNB, stream) == hipSuccess)
      return;
  }
  // fallback: discrete pipeline (identical math, global-read var pass)
  k_moments<<<dim3(NS, BATCH), 256, DYNB, stream>>>(emb, seg, ws);
  k_means  <<<dim3(8, BATCH), 256, 0, stream>>>(ws);
  k_varG   <<<dim3(NS, BATCH), 256, 0, stream>>>(emb, seg, ws);
  k_final  <<<dim3(BATCH), 256, 0, stream>>>(ws);
  k_out    <<<1, 64, 0, stream>>>(ws, out);
}